// Round 3
// baseline (825.869 us; speedup 1.0000x reference)
//
#include <hip/hip_runtime.h>
#include <math.h>

#define Bn  32
#define Cn  1536
#define Tn  2048
#define BNn 128
#define KC  64
#define NCH (Cn / KC)   // 24 K-chunks

typedef __attribute__((ext_vector_type(8))) short bf16x8;
typedef __attribute__((ext_vector_type(4))) float fx4;

// round-to-nearest-even fp32 -> bf16 (as ushort)
__device__ __forceinline__ unsigned int f2bf1(float f) {
    unsigned int u = __float_as_uint(f);
    return (u + 0x7fffu + ((u >> 16) & 1u)) >> 16;
}
__device__ __forceinline__ float fast_tanh(float v) {
    return 1.f - 2.f / (__expf(2.f * v) + 1.f);  // exact saturation at +-inf
}

// ---------------------------------------------------------------------------
// Prep: W_tdnn (BN x C) and W_attn (C x BN) fp32 -> bf16.
// ---------------------------------------------------------------------------
__global__ void k_prep(const float* __restrict__ W1f, const float* __restrict__ Waf,
                       short* __restrict__ W1b, short* __restrict__ Wab) {
    int i = blockIdx.x * 256 + threadIdx.x;
    if (i < BNn * Cn) {
        W1b[i] = (short)f2bf1(W1f[i]);
        Wab[i] = (short)f2bf1(Waf[i]);
    }
}

// ---------------------------------------------------------------------------
// GEMM1: e[b][t][o] = tanh( sum_c x[b][c][t] * W[o][c] + bias[o] )  (e^T layout)
// 128t x 128o tile, K-chunk 64, single-barrier double-buffered LDS pipeline.
// A (x^T, bf16-converted) and B (W bf16) both staged in LDS, 16B-XOR swizzle.
// ---------------------------------------------------------------------------
__global__ __launch_bounds__(256) void k_gemm1(
    const float* __restrict__ x, const short* __restrict__ W1,
    const float* __restrict__ bias, short* __restrict__ e)
{
    __shared__ short sAll[2][2][128 * 64];  // [buf][0=A(x^T) 1=B(W)], 64 KB total

    const int b    = blockIdx.y;
    const int t0   = blockIdx.x * 128;
    const int tid  = threadIdx.x;
    const int lane = tid & 63;
    const int wv   = tid >> 6;
    const int ln   = lane & 15;
    const int g    = lane >> 4;
    const int wt   = (wv & 1) * 64;
    const int wo   = (wv >> 1) * 64;

    const float* xb = x + (size_t)b * Cn * Tn + t0;
    const int t4 = (tid & 31) * 4;   // t quad staged by this thread
    const int cq = (tid >> 5) * 4;   // c quad base

    fx4 acc[4][4];
    #pragma unroll
    for (int i = 0; i < 4; ++i)
        #pragma unroll
        for (int j = 0; j < 4; ++j) acc[i][j] = (fx4){0.f, 0.f, 0.f, 0.f};

    float4 xr[2][4];   // staged x chunk (regs)
    uint4  wr[4];      // staged W chunk (regs)

#define LOADX(k0) { \
    _Pragma("unroll") for (int p = 0; p < 2; ++p) { \
        const int c = cq + p * 32; \
        _Pragma("unroll") for (int j = 0; j < 4; ++j) \
            xr[p][j] = *(const float4*)(xb + (size_t)((k0) + c + j) * Tn + t4); } }

#define LOADW(k0) { \
    _Pragma("unroll") for (int j = 0; j < 4; ++j) { \
        const int p = j * 256 + tid; const int o = p >> 3; const int kb = p & 7; \
        wr[j] = *(const uint4*)(W1 + (size_t)o * Cn + (k0) + kb * 8); } }

#define STAGE(buf) { \
    short* sA = sAll[buf][0]; short* sW = sAll[buf][1]; \
    _Pragma("unroll") for (int p = 0; p < 2; ++p) { \
        const int c = cq + p * 32; const int blk = c >> 3; const int sub = c & 7; \
        _Pragma("unroll") for (int i = 0; i < 4; ++i) { \
            const int t = t4 + i; \
            unsigned int lo = f2bf1(((const float*)&xr[p][0])[i]) | \
                              (f2bf1(((const float*)&xr[p][1])[i]) << 16); \
            unsigned int hi = f2bf1(((const float*)&xr[p][2])[i]) | \
                              (f2bf1(((const float*)&xr[p][3])[i]) << 16); \
            const int idx = t * 64 + ((blk ^ (t & 7)) << 3) + sub; \
            *(uint2*)(sA + idx) = make_uint2(lo, hi); } } \
    _Pragma("unroll") for (int j = 0; j < 4; ++j) { \
        const int p = j * 256 + tid; const int o = p >> 3; const int kb = p & 7; \
        *(uint4*)(sW + o * 64 + ((kb ^ (o & 7)) << 3)) = wr[j]; } }

    // prologue: chunk 0 staged, chunk 1 in regs
    LOADX(0) LOADW(0)
    STAGE(0)
    LOADX(KC) LOADW(KC)

    for (int kc = 0; kc < NCH; ++kc) {
        __syncthreads();  // chunk-kc buffer visible; prior readers of other buf done
        if (kc + 1 < NCH) STAGE((kc + 1) & 1)
        if (kc + 2 < NCH) { LOADX((kc + 2) * KC) LOADW((kc + 2) * KC) }

        const short* sA = sAll[kc & 1][0];
        const short* sW = sAll[kc & 1][1];
        #pragma unroll
        for (int kt = 0; kt < 2; ++kt) {
            bf16x8 af[4], bf[4];
            #pragma unroll
            for (int mm = 0; mm < 4; ++mm) {
                const int t = wt + mm * 16 + ln;
                af[mm] = *(const bf16x8*)(sA + t * 64 + (((kt * 4 + g) ^ (t & 7)) << 3));
            }
            #pragma unroll
            for (int nn = 0; nn < 4; ++nn) {
                const int o = wo + nn * 16 + ln;
                bf[nn] = *(const bf16x8*)(sW + o * 64 + (((kt * 4 + g) ^ (o & 7)) << 3));
            }
            #pragma unroll
            for (int mm = 0; mm < 4; ++mm)
                #pragma unroll
                for (int nn = 0; nn < 4; ++nn)
                    acc[mm][nn] = __builtin_amdgcn_mfma_f32_16x16x32_bf16(
                        af[mm], bf[nn], acc[mm][nn], 0, 0, 0);
        }
    }
#undef LOADX
#undef LOADW
#undef STAGE

    float bs[4];
    #pragma unroll
    for (int nn = 0; nn < 4; ++nn) bs[nn] = bias[wo + nn * 16 + ln];

    short* eb = e + ((size_t)b * Tn + t0 + wt) * BNn + wo;
    #pragma unroll
    for (int mm = 0; mm < 4; ++mm)
        #pragma unroll
        for (int nn = 0; nn < 4; ++nn)
            #pragma unroll
            for (int r = 0; r < 4; ++r) {
                const int t = mm * 16 + g * 4 + r;   // D row = (lane>>4)*4 + reg
                const float v = fast_tanh(acc[mm][nn][r] + bs[nn]);
                eb[(size_t)t * BNn + nn * 16 + ln] = (short)f2bf1(v);
            }
}

// ---------------------------------------------------------------------------
// Kernel 2: a = Wa @ e^T (MFMA K=128), mask, per-lane online softmax + stats.
// 256 thr (4 waves), c-tile 128 (wave: 32 c), T-chunk 64. x staged via LDS
// with coalesced float4 loads; e+x prefetched in regs across the compute phase.
// ---------------------------------------------------------------------------
__global__ __launch_bounds__(256) void k_attn2(
    const float* __restrict__ x, const short* __restrict__ e,
    const short* __restrict__ Wab, const int* __restrict__ mask,
    float* __restrict__ out)
{
    __shared__ short sE[64 * 128];   // [t][k] bf16, swizzled; 16 KB
    __shared__ float sX[128 * 68];   // [c][t] f32, pad 68 (4W%32==16 -> 2-way); 34.8 KB

    const int b    = blockIdx.y;
    const int c0   = blockIdx.x * 128;
    const int tid  = threadIdx.x;
    const int lane = tid & 63;
    const int w    = tid >> 6;
    const int ln   = lane & 15;
    const int g    = lane >> 4;
    const int cw   = c0 + w * 32;

    const float* xb    = x + (size_t)b * Cn * Tn;
    const short* ebase = e + (size_t)b * Tn * BNn;
    const int*   mb    = mask + (size_t)b * Tn;

    // A frags (Wa rows, K=128) resident for the whole kernel
    bf16x8 af[2][4];
    #pragma unroll
    for (int mt = 0; mt < 2; ++mt)
        #pragma unroll
        for (int kt = 0; kt < 4; ++kt)
            af[mt][kt] = *(const bf16x8*)(Wab + (size_t)(cw + mt * 16 + ln) * BNn
                                          + kt * 32 + g * 8);

    float mS[8], S0[8], S1[8], S2[8];
    #pragma unroll
    for (int s = 0; s < 8; ++s) { mS[s] = -1e30f; S0[s] = 0.f; S1[s] = 0.f; S2[s] = 0.f; }

    uint4  ev[4];
    float4 xr4[8];

#define LOADE(tt0) { \
    _Pragma("unroll") for (int j = 0; j < 4; ++j) { \
        const int p = j * 256 + tid; const int t = p >> 4; \
        const int blk = (p & 15) ^ (t & 15); \
        ev[j] = *(const uint4*)(ebase + (size_t)((tt0) + t) * BNn + blk * 8); } }

#define LOADXC(tt0) { \
    _Pragma("unroll") for (int j = 0; j < 8; ++j) { \
        const int row = j * 16 + (tid >> 4); \
        xr4[j] = *(const float4*)(xb + (size_t)(c0 + row) * Tn + (tt0) + (tid & 15) * 4); } }

    LOADE(0) LOADXC(0)

    for (int t0 = 0; t0 < Tn; t0 += 64) {
        __syncthreads();   // readers of previous chunk done
        #pragma unroll
        for (int j = 0; j < 4; ++j)
            *(uint4*)(sE + (size_t)(j * 256 + tid) * 8) = ev[j];
        #pragma unroll
        for (int j = 0; j < 8; ++j)
            *(float4*)(sX + (size_t)(j * 16 + (tid >> 4)) * 68 + (tid & 15) * 4) = xr4[j];
        __syncthreads();

        if (t0 + 64 < Tn) { LOADE(t0 + 64) LOADXC(t0 + 64) }  // fly during compute
        int mv4[4];
        #pragma unroll
        for (int nt = 0; nt < 4; ++nt) mv4[nt] = mb[t0 + nt * 16 + ln];

        fx4 acc[2][4];
        #pragma unroll
        for (int mt = 0; mt < 2; ++mt)
            #pragma unroll
            for (int nt = 0; nt < 4; ++nt) acc[mt][nt] = (fx4){0.f, 0.f, 0.f, 0.f};

        #pragma unroll
        for (int kt = 0; kt < 4; ++kt) {
            bf16x8 bfr[4];
            #pragma unroll
            for (int nt = 0; nt < 4; ++nt) {
                const int t = nt * 16 + ln;
                bfr[nt] = *(const bf16x8*)(sE + t * 128 + (((kt * 4 + g) ^ (t & 15)) << 3));
            }
            #pragma unroll
            for (int mt = 0; mt < 2; ++mt)
                #pragma unroll
                for (int nt = 0; nt < 4; ++nt)
                    acc[mt][nt] = __builtin_amdgcn_mfma_f32_16x16x32_bf16(
                        af[mt][kt], bfr[nt], acc[mt][nt], 0, 0, 0);
        }

        #pragma unroll
        for (int mt = 0; mt < 2; ++mt)
            #pragma unroll
            for (int r = 0; r < 4; ++r) {
                const int s = mt * 4 + r;
                const float* xrow = sX + (size_t)(w * 32 + mt * 16 + g * 4 + r) * 68 + ln;
                float a0 = mv4[0] ? -1e9f : acc[mt][0][r];
                float a1 = mv4[1] ? -1e9f : acc[mt][1][r];
                float a2 = mv4[2] ? -1e9f : acc[mt][2][r];
                float a3 = mv4[3] ? -1e9f : acc[mt][3][r];
                const float mc = fmaxf(fmaxf(a0, a1), fmaxf(a2, a3));
                const float mn = fmaxf(mS[s], mc);
                const float sc = __expf(mS[s] - mn);
                const float p0 = __expf(a0 - mn), p1 = __expf(a1 - mn);
                const float p2 = __expf(a2 - mn), p3 = __expf(a3 - mn);
                const float x0 = xrow[0], x1 = xrow[16], x2 = xrow[32], x3 = xrow[48];
                S0[s] = S0[s] * sc + (p0 + p1 + p2 + p3);
                S1[s] = S1[s] * sc + (p0 * x0 + p1 * x1 + p2 * x2 + p3 * x3);
                S2[s] = S2[s] * sc + (p0 * x0 * x0 + p1 * x1 * x1 + p2 * x2 * x2 + p3 * x3 * x3);
                mS[s] = mn;
            }
    }
#undef LOADE
#undef LOADXC

    // merge the 16 t-partitions (lanes sharing g) with max-rescaling
    #pragma unroll
    for (int s = 0; s < 8; ++s) {
        float m = mS[s], s0 = S0[s], s1 = S1[s], s2 = S2[s];
        #pragma unroll
        for (int off = 1; off < 16; off <<= 1) {
            const float mo = __shfl_xor(m, off);
            const float q0 = __shfl_xor(s0, off);
            const float q1 = __shfl_xor(s1, off);
            const float q2 = __shfl_xor(s2, off);
            const float mn = fmaxf(m, mo);
            const float ea = __expf(m - mn), eb2 = __expf(mo - mn);
            s0 = s0 * ea + q0 * eb2;
            s1 = s1 * ea + q1 * eb2;
            s2 = s2 * ea + q2 * eb2;
            m = mn;
        }
        if (ln == 0) {
            const int c = cw + (s >> 2) * 16 + g * 4 + (s & 3);
            const float mean = s1 / s0;
            const float var  = fmaxf(s2 / s0 - mean * mean, 1e-9f);
            out[(size_t)b * (2 * Cn) + c]      = mean;
            out[(size_t)b * (2 * Cn) + Cn + c] = sqrtf(var);
        }
    }
}

extern "C" void kernel_launch(void* const* d_in, const int* in_sizes, int n_in,
                              void* d_out, int out_size, void* d_ws, size_t ws_size,
                              hipStream_t stream) {
    const float* x      = (const float*)d_in[0];
    const int*   mask   = (const int*)d_in[1];
    const float* W_tdnn = (const float*)d_in[2];
    const float* b_tdnn = (const float*)d_in[3];
    const float* W_attn = (const float*)d_in[4];
    // d_in[5] = b_attn: constant over t per row -> cancels in softmax. Unused.
    float* out = (float*)d_out;

    short* e_bf = (short*)d_ws;                                        // B*T*BN bf16 = 16.78 MB
    short* W1b  = (short*)((char*)d_ws + (size_t)Bn * Tn * BNn * 2);
    short* Wab  = W1b + (size_t)BNn * Cn;

    k_prep<<<dim3((BNn * Cn + 255) / 256), 256, 0, stream>>>(W_tdnn, W_attn, W1b, Wab);
    k_gemm1<<<dim3(Tn / 128, Bn), 256, 0, stream>>>(x, W1b, b_tdnn, e_bf);
    k_attn2<<<dim3(Cn / 128, Bn), 256, 0, stream>>>(x, e_bf, Wab, mask, out);
}